// Round 3
// baseline (331370.752 us; speedup 1.0000x reference)
//
#include <hip/hip_runtime.h>
#include <cstddef>

__device__ __forceinline__ float sigm(float x) { return 1.f / (1.f + __expf(-x)); }
__device__ __forceinline__ float tanh_(float x) { return 1.f - 2.f / (__expf(2.f * x) + 1.f); }

// 16-wide fp32 dot block: accumulates into a0..a3 (declared by caller)
#define DOT16(wp, hp, kk) do { \
    float4 w0_ = *(const float4*)((wp) + (kk));      float4 x0_ = *(const float4*)((hp) + (kk)); \
    float4 w1_ = *(const float4*)((wp) + (kk) + 4);  float4 x1_ = *(const float4*)((hp) + (kk) + 4); \
    float4 w2_ = *(const float4*)((wp) + (kk) + 8);  float4 x2_ = *(const float4*)((hp) + (kk) + 8); \
    float4 w3_ = *(const float4*)((wp) + (kk) + 12); float4 x3_ = *(const float4*)((hp) + (kk) + 12); \
    a0 = fmaf(w0_.x, x0_.x, a0); a0 = fmaf(w0_.y, x0_.y, a0); a0 = fmaf(w0_.z, x0_.z, a0); a0 = fmaf(w0_.w, x0_.w, a0); \
    a1 = fmaf(w1_.x, x1_.x, a1); a1 = fmaf(w1_.y, x1_.y, a1); a1 = fmaf(w1_.z, x1_.z, a1); a1 = fmaf(w1_.w, x1_.w, a1); \
    a2 = fmaf(w2_.x, x2_.x, a2); a2 = fmaf(w2_.y, x2_.y, a2); a2 = fmaf(w2_.z, x2_.z, a2); a2 = fmaf(w2_.w, x2_.w, a2); \
    a3 = fmaf(w3_.x, x3_.x, a3); a3 = fmaf(w3_.y, x3_.y, a3); a3 = fmaf(w3_.z, x3_.z, a3); a3 = fmaf(w3_.w, x3_.w, a3); \
  } while (0)

// ---------------- K1: embed = relu(inputs @ W_e^T + b_e), layout [s][b][e] ----------------
__global__ __launch_bounds__(256) void k_embed(
    const float* __restrict__ inp, const float* __restrict__ We,
    const float* __restrict__ be, float* __restrict__ emb)
{
  __shared__ float sA[32 * 68];    // [kk][m] transposed
  __shared__ float sW[32 * 132];   // [kk][e]
  const int tid = threadIdx.x;
  const int b  = blockIdx.x >> 4;
  const int s0 = (blockIdx.x & 15) << 6;
  float acc[4][8];
#pragma unroll
  for (int i = 0; i < 4; ++i)
#pragma unroll
    for (int j = 0; j < 8; ++j) acc[i][j] = 0.f;
  const int m4 = (tid & 15) << 2;
  const int e8 = (tid >> 4) << 3;
  const float* Ab = inp + ((size_t)(b << 10) + s0) * 1024;
  const int ms = tid >> 2, kq = tid & 3;
  const int es = tid >> 1, kq2 = tid & 1;
  for (int k0 = 0; k0 < 1024; k0 += 32) {
    __syncthreads();
    {
      const float* src = Ab + (size_t)ms * 1024 + k0 + (kq << 3);
      float4 v0 = *(const float4*)(src);
      float4 v1 = *(const float4*)(src + 4);
      int kb = kq << 3;
      sA[(kb+0)*68+ms] = v0.x; sA[(kb+1)*68+ms] = v0.y;
      sA[(kb+2)*68+ms] = v0.z; sA[(kb+3)*68+ms] = v0.w;
      sA[(kb+4)*68+ms] = v1.x; sA[(kb+5)*68+ms] = v1.y;
      sA[(kb+6)*68+ms] = v1.z; sA[(kb+7)*68+ms] = v1.w;
    }
    {
      const float* src = We + (size_t)es * 1024 + k0 + (kq2 << 4);
#pragma unroll
      for (int q = 0; q < 4; ++q) {
        float4 v = *(const float4*)(src + (q << 2));
        int kb = (kq2 << 4) + (q << 2);
        sW[(kb+0)*132+es] = v.x; sW[(kb+1)*132+es] = v.y;
        sW[(kb+2)*132+es] = v.z; sW[(kb+3)*132+es] = v.w;
      }
    }
    __syncthreads();
#pragma unroll 4
    for (int kk = 0; kk < 32; ++kk) {
      float4 a4 = *(const float4*)&sA[kk*68 + m4];
      float4 b0 = *(const float4*)&sW[kk*132 + e8];
      float4 b1 = *(const float4*)&sW[kk*132 + e8 + 4];
      float av[4] = {a4.x, a4.y, a4.z, a4.w};
      float bv[8] = {b0.x, b0.y, b0.z, b0.w, b1.x, b1.y, b1.z, b1.w};
#pragma unroll
      for (int i = 0; i < 4; ++i)
#pragma unroll
        for (int j = 0; j < 8; ++j) acc[i][j] = fmaf(av[i], bv[j], acc[i][j]);
    }
  }
#pragma unroll
  for (int i = 0; i < 4; ++i) {
    int s = s0 + m4 + i;
#pragma unroll
    for (int j = 0; j < 8; ++j) {
      float v = acc[i][j] + be[e8 + j];
      emb[((size_t)(s << 5) + b) * 128 + e8 + j] = v > 0.f ? v : 0.f;
    }
  }
}

// ---------------- K2: a = relu(embed @ Wa1^T + ba1) @ Wa2^T + ba2, layout [s*32+b][3] ----------------
__global__ __launch_bounds__(256) void k_attn(
    const float* __restrict__ emb, const float* __restrict__ Wa1,
    const float* __restrict__ ba1, const float* __restrict__ Wa2,
    const float* __restrict__ ba2, float* __restrict__ aw)
{
  __shared__ float sE[2 * 128];
  __shared__ float sH[2 * 128];
  const int tid = threadIdx.x;
  const int rs0 = blockIdx.x * 2;
  sE[tid] = emb[(size_t)rs0 * 128 + tid];
  __syncthreads();
  const int half = tid >> 7, j = tid & 127;
  const float* w = Wa1 + j * 128;
  const float* e = sE + half * 128;
  float a0 = 0.f, a1 = 0.f, a2 = 0.f, a3 = 0.f;
  for (int k = 0; k < 128; k += 16) DOT16(w, e, k);
  float h = (a0 + a1) + (a2 + a3) + ba1[j];
  sH[half * 128 + j] = h > 0.f ? h : 0.f;
  __syncthreads();
  if (tid < 6) {
    int hh = tid / 3, l = tid % 3;
    const float* w2 = Wa2 + l * 128;
    const float* hv = sH + hh * 128;
    float s = 0.f;
    for (int k = 0; k < 128; ++k) s = fmaf(w2[k], hv[k], s);
    aw[(size_t)(rs0 + hh) * 3 + l] = s + ba2[l];
  }
}

// ---------------- K2b: softmax over time (axis s) per (b, l), in-place ----------------
__global__ __launch_bounds__(256) void k_softmax(float* __restrict__ aw)
{
  __shared__ float red[256];
  const int b = blockIdx.x / 3, l = blockIdx.x % 3;
  const int tid = threadIdx.x;
  float v[4];
#pragma unroll
  for (int i = 0; i < 4; ++i) {
    int s = tid + i * 256;
    v[i] = aw[(size_t)(s * 32 + b) * 3 + l];
  }
  float mx = fmaxf(fmaxf(v[0], v[1]), fmaxf(v[2], v[3]));
  red[tid] = mx;
  __syncthreads();
  for (int off = 128; off > 0; off >>= 1) {
    if (tid < off) red[tid] = fmaxf(red[tid], red[tid + off]);
    __syncthreads();
  }
  mx = red[0];
  __syncthreads();
  float sm = 0.f;
#pragma unroll
  for (int i = 0; i < 4; ++i) sm += __expf(v[i] - mx);
  red[tid] = sm;
  __syncthreads();
  for (int off = 128; off > 0; off >>= 1) {
    if (tid < off) red[tid] += red[tid + off];
    __syncthreads();
  }
  float inv = 1.f / red[0];
#pragma unroll
  for (int i = 0; i < 4; ++i) {
    int s = tid + i * 256;
    aw[(size_t)(s * 32 + b) * 3 + l] = __expf(v[i] - mx) * inv;
  }
}

// ---------------- K_init: initial states + d_out = b_o2 + barrier zero ----------------
__global__ __launch_bounds__(256) void k_init(
    const float* __restrict__ eh0, const float* __restrict__ dh0,
    const float* __restrict__ bo2,
    float* __restrict__ heb, float* __restrict__ hdb,
    float* __restrict__ out, unsigned* __restrict__ bar)
{
  const int i = blockIdx.x * 256 + threadIdx.x;   // 32768 threads
  if (i < 16384) {
    int k = i & 511;
    heb[16384 + i] = eh0[k];   // slot 1 == slot for t=-1
    hdb[16384 + i] = dh0[k];
  }
  out[i] = bo2[0];
  if (i == 0) { bar[0] = 0u; bar[1] = 0u; }
}

// ---------------- device-scope grid barrier (monotone generation counter) ----------------
// Correct across XCDs: __threadfence() emits agent-scope release/acquire cache ops
// (L2 writeback / invalidate) on gfx950; bar atomics are device-scope.
__device__ __forceinline__ void gridbar(unsigned* bar, unsigned target)
{
  __syncthreads();
  if (threadIdx.x == 0) {
    __threadfence();  // release: make our global stores visible to other XCDs
    unsigned old = __hip_atomic_fetch_add(&bar[0], 1u, __ATOMIC_ACQ_REL, __HIP_MEMORY_SCOPE_AGENT);
    if (old == gridDim.x - 1) {
      __hip_atomic_store(&bar[0], 0u, __ATOMIC_RELAXED, __HIP_MEMORY_SCOPE_AGENT);
      __hip_atomic_fetch_add(&bar[1], 1u, __ATOMIC_RELEASE, __HIP_MEMORY_SCOPE_AGENT);
    } else {
      while (__hip_atomic_load(&bar[1], __ATOMIC_ACQUIRE, __HIP_MEMORY_SCOPE_AGENT) < target)
        __builtin_amdgcn_s_sleep(1);
    }
    __threadfence();  // acquire: invalidate stale cache lines before reading others' data
  }
  __syncthreads();
}

// ---------------- K_persist: whole recurrent pipeline ----------------
// PLAIN launch, 256 wgs x 256 thr. Residency guarantee: 55.5 KB static LDS -> 2 blocks/CU
// by LDS; __launch_bounds__(256,2) -> VGPR <= 256 -> >= 2 blocks/CU by registers.
// Capacity 512 >= grid 256, so ALL wgs are resident under any packing -> barrier can't deadlock.
// wg g owns enc+dec h-indices {2g, 2g+1} (8 gate rows each); wgs 0..127 also own W_o1 row g.
__global__ __launch_bounds__(256, 2) void k_persist(
    const float* __restrict__ emb, const float* __restrict__ aw,
    const int* __restrict__ lens,
    const float* __restrict__ Wih_e, const float* __restrict__ Whh_e,
    const float* __restrict__ bih_e, const float* __restrict__ bhh_e,
    const float* __restrict__ Wih_d, const float* __restrict__ Whh_d,
    const float* __restrict__ bih_d, const float* __restrict__ bhh_d,
    const float* __restrict__ ec0, const float* __restrict__ dc0,
    const float* __restrict__ Wo1, const float* __restrict__ bo1,
    const float* __restrict__ Wo2, const float* __restrict__ maskp,
    float* __restrict__ heb, float* __restrict__ hdb,
    float* __restrict__ ctxb, float* __restrict__ out,
    unsigned* __restrict__ bar)
{
  __shared__ float sWe[8 * 516];    // Whh_e rows, stride 516 (bank-offset 4/row)
  __shared__ float sWxe[8 * 132];   // Wih_e rows
  __shared__ float sWd[8 * 1028];   // [0..511]=Wih_d[.,1:] (ctx), [512..1023]=Whh_d, [1024]=Wih_d[.,0] (p)
  __shared__ float sWo[512];        // W_o1 row g (wgs < 128)
  __shared__ float sB[8], sBd[8];
  __shared__ float sG[8 * 33];
  const int tid = threadIdx.x;
  const int g = blockIdx.x;
  const int j0 = g << 1;

  // ---- one-time weight staging (lives in LDS for all 1024 steps) ----
  for (int i = tid; i < 8 * 512; i += 256) {
    int r = i >> 9, k = i & 511;
    int row = ((r >> 1) << 9) + j0 + (r & 1);
    sWe[r * 516 + k] = Whh_e[(size_t)row * 512 + k];
  }
  for (int i = tid; i < 8 * 128; i += 256) {
    int r = i >> 7, e = i & 127;
    int row = ((r >> 1) << 9) + j0 + (r & 1);
    sWxe[r * 132 + e] = Wih_e[(size_t)row * 128 + e];
  }
  for (int i = tid; i < 8 * 1025; i += 256) {
    int r = i / 1025, q = i % 1025;
    int row = ((r >> 1) << 9) + j0 + (r & 1);
    float v;
    if (q < 512)       v = Wih_d[(size_t)row * 513 + 1 + q];
    else if (q < 1024) v = Whh_d[(size_t)row * 512 + (q - 512)];
    else               v = Wih_d[(size_t)row * 513];
    sWd[r * 1028 + q] = v;
  }
  if (tid < 8) {
    int row = ((tid >> 1) << 9) + j0 + (tid & 1);
    sB[tid]  = bih_e[row] + bhh_e[row];
    sBd[tid] = bih_d[row] + bhh_d[row];
  }
  float bo1g = 0.f, wo2g = 0.f;
  if (g < 128) {
    for (int i = tid; i < 512; i += 256) sWo[i] = Wo1[(size_t)g * 512 + i];
    bo1g = bo1[g]; wo2g = Wo2[g];
  }
  // ---- register-resident state (wave 0, tid<64): c_e, c_d, masked-h ring, length ----
  float c_e = 0.f, c_d = 0.f, hm1 = 0.f, hm2 = 0.f;
  int len_b = 0;
  if (tid < 64) {
    int jl = tid & 1, b2 = tid >> 1;
    c_e = ec0[j0 + jl];
    c_d = dc0[j0 + jl];
    len_b = lens[b2];
  }
  __syncthreads();

  unsigned bgen = 1;
  const int r = tid & 7, bb = tid >> 3;

  for (int t = 0; t < 1024; ++t) {
    const float* heprev = heb + (size_t)((t + 1) & 1) * 16384;
    const float* hdprev = hdb + (size_t)((t + 1) & 1) * 16384;

    // ---- phase A part 1: output-layer duty for step t-1 (wgs < 128) ----
    if (g < 128 && t > 0) {
      const float* hd = hdprev + bb * 512 + r * 64;
      const float* wo = sWo + r * 64;
      float a0 = 0.f, a1 = 0.f, a2 = 0.f, a3 = 0.f;
      DOT16(wo, hd, 0); DOT16(wo, hd, 16); DOT16(wo, hd, 32); DOT16(wo, hd, 48);
      float s_ = (a0 + a1) + (a2 + a3);
      s_ += __shfl_down(s_, 4, 8);
      s_ += __shfl_down(s_, 2, 8);
      s_ += __shfl_down(s_, 1, 8);
      if (r == 0) {
        float q_ = s_ + bo1g;
        q_ = q_ > 0.f ? q_ : 0.f;
        atomicAdd(&out[bb * 1024 + (t - 1)], q_ * wo2g);
      }
    }

    // ---- phase A part 2: encoder gates (weights from LDS, h/x from global) ----
    {
      const float* wr = sWe + r * 516;
      const float* hb = heprev + bb * 512;
      float a0 = 0.f, a1 = 0.f, a2 = 0.f, a3 = 0.f;
      for (int k = 0; k < 512; k += 16) DOT16(wr, hb, k);
      const float* wx = sWxe + r * 132;
      const float* xb = emb + (size_t)(t * 32 + bb) * 128;
      for (int k = 0; k < 128; k += 16) DOT16(wx, xb, k);
      sG[r * 33 + bb] = (a0 + a1) + (a2 + a3) + sB[r];
    }
    __syncthreads();

    // ---- phase A part 3: enc cell + publish h_e, ctx (register hm ring) ----
    if (tid < 64) {
      int jl = tid & 1, b2 = tid >> 1;
      int ci = (b2 << 9) + j0 + jl;
      float gi = sG[(0 + jl) * 33 + b2];
      float gf = sG[(2 + jl) * 33 + b2];
      float gg = sG[(4 + jl) * 33 + b2];
      float go = sG[(6 + jl) * 33 + b2];
      c_e = sigm(gf) * c_e + sigm(gi) * tanh_(gg);
      float h = sigm(go) * tanh_(c_e);
      heb[(size_t)(t & 1) * 16384 + ci] = h;
      float hmv = (t < len_b) ? h : 0.f;
      const float* at = aw + (size_t)(t * 32 + b2) * 3;
      float ctx = at[0] * hmv + at[1] * hm1 + at[2] * hm2;
      hm2 = hm1; hm1 = hmv;
      ctxb[ci] = ctx;
    }
    gridbar(bar, bgen++);

    // ---- phase B: decoder gates + cell ----
    {
      const float* wh = sWd + r * 1028 + 512;
      const float* hb = hdprev + bb * 512;
      float a0 = 0.f, a1 = 0.f, a2 = 0.f, a3 = 0.f;
      for (int k = 0; k < 512; k += 16) DOT16(wh, hb, k);
      const float* wc = sWd + r * 1028;
      const float* cb = ctxb + bb * 512;
      for (int k = 0; k < 512; k += 16) DOT16(wc, cb, k);
      float pv = (t == 0) ? 0.f : out[bb * 1024 + (t - 1)];
      sG[r * 33 + bb] = (a0 + a1) + (a2 + a3) + pv * sWd[r * 1028 + 1024] + sBd[r];
    }
    __syncthreads();
    if (tid < 64) {
      int jl = tid & 1, b2 = tid >> 1;
      int ci = (b2 << 9) + j0 + jl;
      float gi = sG[(0 + jl) * 33 + b2];
      float gf = sG[(2 + jl) * 33 + b2];
      float gg = sG[(4 + jl) * 33 + b2];
      float go = sG[(6 + jl) * 33 + b2];
      c_d = sigm(gf) * c_d + sigm(gi) * tanh_(gg);
      float h = sigm(go) * tanh_(c_d);
      hdb[(size_t)(t & 1) * 16384 + ci] = h;
    }
    gridbar(bar, bgen++);
  }

  // ---- final output-layer duty for t = 1023 (h_d(1023) is in slot 1) ----
  if (g < 128) {
    const float* hd = hdb + 16384 + bb * 512 + r * 64;  // 1023 & 1 == 1
    const float* wo = sWo + r * 64;
    float a0 = 0.f, a1 = 0.f, a2 = 0.f, a3 = 0.f;
    DOT16(wo, hd, 0); DOT16(wo, hd, 16); DOT16(wo, hd, 32); DOT16(wo, hd, 48);
    float s_ = (a0 + a1) + (a2 + a3);
    s_ += __shfl_down(s_, 4, 8);
    s_ += __shfl_down(s_, 2, 8);
    s_ += __shfl_down(s_, 1, 8);
    if (r == 0) {
      float q_ = s_ + bo1g;
      q_ = q_ > 0.f ? q_ : 0.f;
      atomicAdd(&out[bb * 1024 + 1023], q_ * wo2g);
    }
  }
  gridbar(bar, bgen++);

  // ---- apply mask: out[b][s] *= mask[b][s] ----
  if (tid < 128) {
    int i = g * 128 + tid;
    out[i] *= maskp[i];
  }
}

extern "C" void kernel_launch(void* const* d_in, const int* in_sizes, int n_in,
                              void* d_out, int out_size, void* d_ws, size_t ws_size,
                              hipStream_t stream)
{
  const float* inp   = (const float*)d_in[0];
  const float* maskp = (const float*)d_in[1];
  const int*   lens  = (const int*)d_in[2];
  const float* We    = (const float*)d_in[3];
  const float* be    = (const float*)d_in[4];
  const float* Wa1   = (const float*)d_in[5];
  const float* ba1   = (const float*)d_in[6];
  const float* Wa2   = (const float*)d_in[7];
  const float* ba2   = (const float*)d_in[8];
  const float* Wih_e = (const float*)d_in[9];
  const float* Whh_e = (const float*)d_in[10];
  const float* bih_e = (const float*)d_in[11];
  const float* bhh_e = (const float*)d_in[12];
  const float* eh0   = (const float*)d_in[13];
  const float* ec0   = (const float*)d_in[14];
  const float* Wih_d = (const float*)d_in[15];
  const float* Whh_d = (const float*)d_in[16];
  const float* bih_d = (const float*)d_in[17];
  const float* bhh_d = (const float*)d_in[18];
  const float* dh0   = (const float*)d_in[19];
  const float* dc0   = (const float*)d_in[20];
  const float* Wo1   = (const float*)d_in[21];
  const float* bo1   = (const float*)d_in[22];
  const float* Wo2   = (const float*)d_in[23];
  const float* bo2   = (const float*)d_in[24];

  float* ws   = (float*)d_ws;
  float* emb  = ws;                  // 4,194,304 floats  [s][b][e]
  float* aw   = emb + 4194304;       //    98,304 floats  [s*32+b][3]
  float* heb  = aw + 98304;          //    32,768 floats  [2][b][h]
  float* hdb  = heb + 32768;         //    32,768
  float* ctxb = hdb + 32768;         //    16,384 (single buffer: phases are barrier-separated)
  unsigned* bar = (unsigned*)(ctxb + 16384);
  float* outf = (float*)d_out;

  k_embed<<<512, 256, 0, stream>>>(inp, We, be, emb);
  k_attn<<<16384, 256, 0, stream>>>(emb, Wa1, ba1, Wa2, ba2, aw);
  k_softmax<<<96, 256, 0, stream>>>(aw);
  k_init<<<128, 256, 0, stream>>>(eh0, dh0, bo2, heb, hdb, outf, bar);

  k_persist<<<256, 256, 0, stream>>>(
      emb, aw, lens,
      Wih_e, Whh_e, bih_e, bhh_e,
      Wih_d, Whh_d, bih_d, bhh_d,
      ec0, dc0, Wo1, bo1, Wo2, maskp,
      heb, hdb, ctxb, outf, bar);
}

// Round 5
// 265932.666 us; speedup vs baseline: 1.2461x; 1.2461x over previous
//
#include <hip/hip_runtime.h>
#include <cstddef>

__device__ __forceinline__ float sigm(float x) { return 1.f / (1.f + __expf(-x)); }
__device__ __forceinline__ float tanh_(float x) { return 1.f - 2.f / (__expf(2.f * x) + 1.f); }

// 16-wide fp32 dot block: accumulates into a0..a3 (declared by caller)
#define DOT16(wp, hp, kk) do { \
    float4 w0_ = *(const float4*)((wp) + (kk));      float4 x0_ = *(const float4*)((hp) + (kk)); \
    float4 w1_ = *(const float4*)((wp) + (kk) + 4);  float4 x1_ = *(const float4*)((hp) + (kk) + 4); \
    float4 w2_ = *(const float4*)((wp) + (kk) + 8);  float4 x2_ = *(const float4*)((hp) + (kk) + 8); \
    float4 w3_ = *(const float4*)((wp) + (kk) + 12); float4 x3_ = *(const float4*)((hp) + (kk) + 12); \
    a0 = fmaf(w0_.x, x0_.x, a0); a0 = fmaf(w0_.y, x0_.y, a0); a0 = fmaf(w0_.z, x0_.z, a0); a0 = fmaf(w0_.w, x0_.w, a0); \
    a1 = fmaf(w1_.x, x1_.x, a1); a1 = fmaf(w1_.y, x1_.y, a1); a1 = fmaf(w1_.z, x1_.z, a1); a1 = fmaf(w1_.w, x1_.w, a1); \
    a2 = fmaf(w2_.x, x2_.x, a2); a2 = fmaf(w2_.y, x2_.y, a2); a2 = fmaf(w2_.z, x2_.z, a2); a2 = fmaf(w2_.w, x2_.w, a2); \
    a3 = fmaf(w3_.x, x3_.x, a3); a3 = fmaf(w3_.y, x3_.y, a3); a3 = fmaf(w3_.z, x3_.z, a3); a3 = fmaf(w3_.w, x3_.w, a3); \
  } while (0)

// ---------------- K1: embed = relu(inputs @ W_e^T + b_e), layout [s][b][e] ----------------
__global__ __launch_bounds__(256) void k_embed(
    const float* __restrict__ inp, const float* __restrict__ We,
    const float* __restrict__ be, float* __restrict__ emb)
{
  __shared__ float sA[32 * 68];    // [kk][m] transposed
  __shared__ float sW[32 * 132];   // [kk][e]
  const int tid = threadIdx.x;
  const int b  = blockIdx.x >> 4;
  const int s0 = (blockIdx.x & 15) << 6;
  float acc[4][8];
#pragma unroll
  for (int i = 0; i < 4; ++i)
#pragma unroll
    for (int j = 0; j < 8; ++j) acc[i][j] = 0.f;
  const int m4 = (tid & 15) << 2;
  const int e8 = (tid >> 4) << 3;
  const float* Ab = inp + ((size_t)(b << 10) + s0) * 1024;
  const int ms = tid >> 2, kq = tid & 3;
  const int es = tid >> 1, kq2 = tid & 1;
  for (int k0 = 0; k0 < 1024; k0 += 32) {
    __syncthreads();
    {
      const float* src = Ab + (size_t)ms * 1024 + k0 + (kq << 3);
      float4 v0 = *(const float4*)(src);
      float4 v1 = *(const float4*)(src + 4);
      int kb = kq << 3;
      sA[(kb+0)*68+ms] = v0.x; sA[(kb+1)*68+ms] = v0.y;
      sA[(kb+2)*68+ms] = v0.z; sA[(kb+3)*68+ms] = v0.w;
      sA[(kb+4)*68+ms] = v1.x; sA[(kb+5)*68+ms] = v1.y;
      sA[(kb+6)*68+ms] = v1.z; sA[(kb+7)*68+ms] = v1.w;
    }
    {
      const float* src = We + (size_t)es * 1024 + k0 + (kq2 << 4);
#pragma unroll
      for (int q = 0; q < 4; ++q) {
        float4 v = *(const float4*)(src + (q << 2));
        int kb = (kq2 << 4) + (q << 2);
        sW[(kb+0)*132+es] = v.x; sW[(kb+1)*132+es] = v.y;
        sW[(kb+2)*132+es] = v.z; sW[(kb+3)*132+es] = v.w;
      }
    }
    __syncthreads();
#pragma unroll 4
    for (int kk = 0; kk < 32; ++kk) {
      float4 a4 = *(const float4*)&sA[kk*68 + m4];
      float4 b0 = *(const float4*)&sW[kk*132 + e8];
      float4 b1 = *(const float4*)&sW[kk*132 + e8 + 4];
      float av[4] = {a4.x, a4.y, a4.z, a4.w};
      float bv[8] = {b0.x, b0.y, b0.z, b0.w, b1.x, b1.y, b1.z, b1.w};
#pragma unroll
      for (int i = 0; i < 4; ++i)
#pragma unroll
        for (int j = 0; j < 8; ++j) acc[i][j] = fmaf(av[i], bv[j], acc[i][j]);
    }
  }
#pragma unroll
  for (int i = 0; i < 4; ++i) {
    int s = s0 + m4 + i;
#pragma unroll
    for (int j = 0; j < 8; ++j) {
      float v = acc[i][j] + be[e8 + j];
      emb[((size_t)(s << 5) + b) * 128 + e8 + j] = v > 0.f ? v : 0.f;
    }
  }
}

// ---------------- K2: a = relu(embed @ Wa1^T + ba1) @ Wa2^T + ba2, layout [s*32+b][3] ----------------
__global__ __launch_bounds__(256) void k_attn(
    const float* __restrict__ emb, const float* __restrict__ Wa1,
    const float* __restrict__ ba1, const float* __restrict__ Wa2,
    const float* __restrict__ ba2, float* __restrict__ aw)
{
  __shared__ float sE[2 * 128];
  __shared__ float sH[2 * 128];
  const int tid = threadIdx.x;
  const int rs0 = blockIdx.x * 2;
  sE[tid] = emb[(size_t)rs0 * 128 + tid];
  __syncthreads();
  const int half = tid >> 7, j = tid & 127;
  const float* w = Wa1 + j * 128;
  const float* e = sE + half * 128;
  float a0 = 0.f, a1 = 0.f, a2 = 0.f, a3 = 0.f;
  for (int k = 0; k < 128; k += 16) DOT16(w, e, k);
  float h = (a0 + a1) + (a2 + a3) + ba1[j];
  sH[half * 128 + j] = h > 0.f ? h : 0.f;
  __syncthreads();
  if (tid < 6) {
    int hh = tid / 3, l = tid % 3;
    const float* w2 = Wa2 + l * 128;
    const float* hv = sH + hh * 128;
    float s = 0.f;
    for (int k = 0; k < 128; ++k) s = fmaf(w2[k], hv[k], s);
    aw[(size_t)(rs0 + hh) * 3 + l] = s + ba2[l];
  }
}

// ---------------- K2b: softmax over time (axis s) per (b, l), in-place ----------------
__global__ __launch_bounds__(256) void k_softmax(float* __restrict__ aw)
{
  __shared__ float red[256];
  const int b = blockIdx.x / 3, l = blockIdx.x % 3;
  const int tid = threadIdx.x;
  float v[4];
#pragma unroll
  for (int i = 0; i < 4; ++i) {
    int s = tid + i * 256;
    v[i] = aw[(size_t)(s * 32 + b) * 3 + l];
  }
  float mx = fmaxf(fmaxf(v[0], v[1]), fmaxf(v[2], v[3]));
  red[tid] = mx;
  __syncthreads();
  for (int off = 128; off > 0; off >>= 1) {
    if (tid < off) red[tid] = fmaxf(red[tid], red[tid + off]);
    __syncthreads();
  }
  mx = red[0];
  __syncthreads();
  float sm = 0.f;
#pragma unroll
  for (int i = 0; i < 4; ++i) sm += __expf(v[i] - mx);
  red[tid] = sm;
  __syncthreads();
  for (int off = 128; off > 0; off >>= 1) {
    if (tid < off) red[tid] += red[tid + off];
    __syncthreads();
  }
  float inv = 1.f / red[0];
#pragma unroll
  for (int i = 0; i < 4; ++i) {
    int s = tid + i * 256;
    aw[(size_t)(s * 32 + b) * 3 + l] = __expf(v[i] - mx) * inv;
  }
}

// ---------------- K_init: initial states + d_out = b_o2 + barrier zero ----------------
__global__ __launch_bounds__(256) void k_init(
    const float* __restrict__ eh0, const float* __restrict__ dh0,
    const float* __restrict__ bo2,
    float* __restrict__ heb, float* __restrict__ hdb,
    float* __restrict__ out, unsigned* __restrict__ bar)
{
  const int i = blockIdx.x * 256 + threadIdx.x;   // 32768 threads
  if (i < 16384) {
    int k = i & 511;
    heb[16384 + i] = eh0[k];   // slot 1 == slot for t=-1
    hdb[16384 + i] = dh0[k];
  }
  out[i] = bo2[0];
  if (i < 1024) bar[i] = 0u;   // leaves, root, release flag
}

// ---------------- device-scope grid barrier: hierarchical, fence-minimal ----------------
// bar layout (unsigned, 64B-separated): leaf[i] = bar[i*16] (i<32, 8 wgs each),
// root = bar[32*16], release flag = bar[33*16]. Monotone generation counters, no resets.
// Correctness: agent-scope release fence (buffer_wbl2 + waitcnt) completes BEFORE the
// arrive RMW issues; waiters do ONE agent-scope acquire fence (buffer_inv) after
// observing flag >= gen. Poll loads are RELAXED -> no cache-maintenance per iteration
// (the R3 disaster: acquire-per-poll emitted chip-wide L2 invalidates -> 732 GB HBM).
__device__ __forceinline__ void gridbar(unsigned* bar, unsigned gen)
{
  __syncthreads();
  if (threadIdx.x == 0) {
    __builtin_amdgcn_fence(__ATOMIC_RELEASE, "agent");
    unsigned* leaf = bar + ((blockIdx.x >> 3) << 4);
    unsigned* root = bar + (32 << 4);
    unsigned* flag = bar + (33 << 4);
    unsigned old = __hip_atomic_fetch_add(leaf, 1u, __ATOMIC_RELAXED, __HIP_MEMORY_SCOPE_AGENT);
    if (old == (gen << 3) - 1u) {                 // last of this leaf's 8 wgs
      unsigned r = __hip_atomic_fetch_add(root, 1u, __ATOMIC_RELAXED, __HIP_MEMORY_SCOPE_AGENT);
      if (r == (gen << 5) - 1u)                   // last of the 32 leaves
        __hip_atomic_store(flag, gen, __ATOMIC_RELAXED, __HIP_MEMORY_SCOPE_AGENT);
    }
    while (__hip_atomic_load(flag, __ATOMIC_RELAXED, __HIP_MEMORY_SCOPE_AGENT) < gen)
      __builtin_amdgcn_s_sleep(2);
    __builtin_amdgcn_fence(__ATOMIC_ACQUIRE, "agent");
  }
  __syncthreads();
}

// ---------------- K_persist: whole recurrent pipeline ----------------
// PLAIN launch, 256 wgs x 256 thr. Residency: 56.8 KB LDS -> 2 blocks/CU; VGPR 128 (R3
// measured) -> capacity 512 >= grid 256 under any packing -> barrier cannot deadlock.
// wg g owns enc+dec h-indices {2g, 2g+1} (8 gate rows each); wgs 0..127 also own W_o1 row g.
__global__ __launch_bounds__(256, 2) void k_persist(
    const float* __restrict__ emb, const float* __restrict__ aw,
    const int* __restrict__ lens,
    const float* __restrict__ Wih_e, const float* __restrict__ Whh_e,
    const float* __restrict__ bih_e, const float* __restrict__ bhh_e,
    const float* __restrict__ Wih_d, const float* __restrict__ Whh_d,
    const float* __restrict__ bih_d, const float* __restrict__ bhh_d,
    const float* __restrict__ ec0, const float* __restrict__ dc0,
    const float* __restrict__ Wo1, const float* __restrict__ bo1,
    const float* __restrict__ Wo2, const float* __restrict__ maskp,
    float* __restrict__ heb, float* __restrict__ hdb,
    float* __restrict__ ctxb, float* __restrict__ out,
    unsigned* __restrict__ bar)
{
  __shared__ float sWe[8 * 516];    // Whh_e rows, stride 516 (bank-offset 4/row)
  __shared__ float sWxe[8 * 132];   // Wih_e rows
  __shared__ float sWd[8 * 1028];   // [0..511]=Wih_d[.,1:] (ctx), [512..1023]=Whh_d, [1024]=Wih_d[.,0] (p)
  __shared__ float sWo[512];        // W_o1 row g (wgs < 128)
  __shared__ float sB[8], sBd[8];
  __shared__ float sG[8 * 33];
  const int tid = threadIdx.x;
  const int g = blockIdx.x;
  const int j0 = g << 1;

  // ---- one-time weight staging (lives in LDS for all 1024 steps) ----
  for (int i = tid; i < 8 * 512; i += 256) {
    int r = i >> 9, k = i & 511;
    int row = ((r >> 1) << 9) + j0 + (r & 1);
    sWe[r * 516 + k] = Whh_e[(size_t)row * 512 + k];
  }
  for (int i = tid; i < 8 * 128; i += 256) {
    int r = i >> 7, e = i & 127;
    int row = ((r >> 1) << 9) + j0 + (r & 1);
    sWxe[r * 132 + e] = Wih_e[(size_t)row * 128 + e];
  }
  for (int i = tid; i < 8 * 1025; i += 256) {
    int r = i / 1025, q = i % 1025;
    int row = ((r >> 1) << 9) + j0 + (r & 1);
    float v;
    if (q < 512)       v = Wih_d[(size_t)row * 513 + 1 + q];
    else if (q < 1024) v = Whh_d[(size_t)row * 512 + (q - 512)];
    else               v = Wih_d[(size_t)row * 513];
    sWd[r * 1028 + q] = v;
  }
  if (tid < 8) {
    int row = ((tid >> 1) << 9) + j0 + (tid & 1);
    sB[tid]  = bih_e[row] + bhh_e[row];
    sBd[tid] = bih_d[row] + bhh_d[row];
  }
  float bo1g = 0.f, wo2g = 0.f;
  if (g < 128) {
    for (int i = tid; i < 512; i += 256) sWo[i] = Wo1[(size_t)g * 512 + i];
    bo1g = bo1[g]; wo2g = Wo2[g];
  }
  // ---- register-resident state (wave 0, tid<64): c_e, c_d, masked-h ring, length ----
  float c_e = 0.f, c_d = 0.f, hm1 = 0.f, hm2 = 0.f;
  int len_b = 0;
  if (tid < 64) {
    int jl = tid & 1, b2 = tid >> 1;
    c_e = ec0[j0 + jl];
    c_d = dc0[j0 + jl];
    len_b = lens[b2];
  }
  __syncthreads();

  unsigned bgen = 1;
  const int r = tid & 7, bb = tid >> 3;

  for (int t = 0; t < 1024; ++t) {
    const float* heprev = heb + (size_t)((t + 1) & 1) * 16384;
    const float* hdprev = hdb + (size_t)((t + 1) & 1) * 16384;

    // ---- phase A part 1: output-layer duty for step t-1 (wgs < 128) ----
    if (g < 128 && t > 0) {
      const float* hd = hdprev + bb * 512 + r * 64;
      const float* wo = sWo + r * 64;
      float a0 = 0.f, a1 = 0.f, a2 = 0.f, a3 = 0.f;
      DOT16(wo, hd, 0); DOT16(wo, hd, 16); DOT16(wo, hd, 32); DOT16(wo, hd, 48);
      float s_ = (a0 + a1) + (a2 + a3);
      s_ += __shfl_down(s_, 4, 8);
      s_ += __shfl_down(s_, 2, 8);
      s_ += __shfl_down(s_, 1, 8);
      if (r == 0) {
        float q_ = s_ + bo1g;
        q_ = q_ > 0.f ? q_ : 0.f;
        atomicAdd(&out[bb * 1024 + (t - 1)], q_ * wo2g);
      }
    }

    // ---- phase A part 2: encoder gates (weights from LDS, h/x from global) ----
    {
      const float* wr = sWe + r * 516;
      const float* hb = heprev + bb * 512;
      float a0 = 0.f, a1 = 0.f, a2 = 0.f, a3 = 0.f;
      for (int k = 0; k < 512; k += 16) DOT16(wr, hb, k);
      const float* wx = sWxe + r * 132;
      const float* xb = emb + (size_t)(t * 32 + bb) * 128;
      for (int k = 0; k < 128; k += 16) DOT16(wx, xb, k);
      sG[r * 33 + bb] = (a0 + a1) + (a2 + a3) + sB[r];
    }
    __syncthreads();

    // ---- phase A part 3: enc cell + publish h_e, ctx (register hm ring) ----
    if (tid < 64) {
      int jl = tid & 1, b2 = tid >> 1;
      int ci = (b2 << 9) + j0 + jl;
      float gi = sG[(0 + jl) * 33 + b2];
      float gf = sG[(2 + jl) * 33 + b2];
      float gg = sG[(4 + jl) * 33 + b2];
      float go = sG[(6 + jl) * 33 + b2];
      c_e = sigm(gf) * c_e + sigm(gi) * tanh_(gg);
      float h = sigm(go) * tanh_(c_e);
      heb[(size_t)(t & 1) * 16384 + ci] = h;
      float hmv = (t < len_b) ? h : 0.f;
      const float* at = aw + (size_t)(t * 32 + b2) * 3;
      float ctx = at[0] * hmv + at[1] * hm1 + at[2] * hm2;
      hm2 = hm1; hm1 = hmv;
      ctxb[ci] = ctx;
    }
    gridbar(bar, bgen++);

    // ---- phase B: decoder gates + cell ----
    {
      const float* wh = sWd + r * 1028 + 512;
      const float* hb = hdprev + bb * 512;
      float a0 = 0.f, a1 = 0.f, a2 = 0.f, a3 = 0.f;
      for (int k = 0; k < 512; k += 16) DOT16(wh, hb, k);
      const float* wc = sWd + r * 1028;
      const float* cb = ctxb + bb * 512;
      for (int k = 0; k < 512; k += 16) DOT16(wc, cb, k);
      float pv = (t == 0) ? 0.f : out[bb * 1024 + (t - 1)];
      sG[r * 33 + bb] = (a0 + a1) + (a2 + a3) + pv * sWd[r * 1028 + 1024] + sBd[r];
    }
    __syncthreads();
    if (tid < 64) {
      int jl = tid & 1, b2 = tid >> 1;
      int ci = (b2 << 9) + j0 + jl;
      float gi = sG[(0 + jl) * 33 + b2];
      float gf = sG[(2 + jl) * 33 + b2];
      float gg = sG[(4 + jl) * 33 + b2];
      float go = sG[(6 + jl) * 33 + b2];
      c_d = sigm(gf) * c_d + sigm(gi) * tanh_(gg);
      float h = sigm(go) * tanh_(c_d);
      hdb[(size_t)(t & 1) * 16384 + ci] = h;
    }
    gridbar(bar, bgen++);
  }

  // ---- final output-layer duty for t = 1023 (h_d(1023) is in slot 1) ----
  if (g < 128) {
    const float* hd = hdb + 16384 + bb * 512 + r * 64;  // 1023 & 1 == 1
    const float* wo = sWo + r * 64;
    float a0 = 0.f, a1 = 0.f, a2 = 0.f, a3 = 0.f;
    DOT16(wo, hd, 0); DOT16(wo, hd, 16); DOT16(wo, hd, 32); DOT16(wo, hd, 48);
    float s_ = (a0 + a1) + (a2 + a3);
    s_ += __shfl_down(s_, 4, 8);
    s_ += __shfl_down(s_, 2, 8);
    s_ += __shfl_down(s_, 1, 8);
    if (r == 0) {
      float q_ = s_ + bo1g;
      q_ = q_ > 0.f ? q_ : 0.f;
      atomicAdd(&out[bb * 1024 + 1023], q_ * wo2g);
    }
  }
  gridbar(bar, bgen++);

  // ---- apply mask: out[b][s] *= mask[b][s] ----
  if (tid < 128) {
    int i = g * 128 + tid;
    out[i] *= maskp[i];
  }
}

extern "C" void kernel_launch(void* const* d_in, const int* in_sizes, int n_in,
                              void* d_out, int out_size, void* d_ws, size_t ws_size,
                              hipStream_t stream)
{
  const float* inp   = (const float*)d_in[0];
  const float* maskp = (const float*)d_in[1];
  const int*   lens  = (const int*)d_in[2];
  const float* We    = (const float*)d_in[3];
  const float* be    = (const float*)d_in[4];
  const float* Wa1   = (const float*)d_in[5];
  const float* ba1   = (const float*)d_in[6];
  const float* Wa2   = (const float*)d_in[7];
  const float* ba2   = (const float*)d_in[8];
  const float* Wih_e = (const float*)d_in[9];
  const float* Whh_e = (const float*)d_in[10];
  const float* bih_e = (const float*)d_in[11];
  const float* bhh_e = (const float*)d_in[12];
  const float* eh0   = (const float*)d_in[13];
  const float* ec0   = (const float*)d_in[14];
  const float* Wih_d = (const float*)d_in[15];
  const float* Whh_d = (const float*)d_in[16];
  const float* bih_d = (const float*)d_in[17];
  const float* bhh_d = (const float*)d_in[18];
  const float* dh0   = (const float*)d_in[19];
  const float* dc0   = (const float*)d_in[20];
  const float* Wo1   = (const float*)d_in[21];
  const float* bo1   = (const float*)d_in[22];
  const float* Wo2   = (const float*)d_in[23];
  const float* bo2   = (const float*)d_in[24];

  float* ws   = (float*)d_ws;
  float* emb  = ws;                  // 4,194,304 floats  [s][b][e]
  float* aw   = emb + 4194304;       //    98,304 floats  [s*32+b][3]
  float* heb  = aw + 98304;          //    32,768 floats  [2][b][h]
  float* hdb  = heb + 32768;         //    32,768
  float* ctxb = hdb + 32768;         //    16,384 (single buffer: phases are barrier-separated)
  unsigned* bar = (unsigned*)(ctxb + 16384);   // 1024 uints (leaves/root/flag, 64B-spaced)
  float* outf = (float*)d_out;

  k_embed<<<512, 256, 0, stream>>>(inp, We, be, emb);
  k_attn<<<16384, 256, 0, stream>>>(emb, Wa1, ba1, Wa2, ba2, aw);
  k_softmax<<<96, 256, 0, stream>>>(aw);
  k_init<<<128, 256, 0, stream>>>(eh0, dh0, bo2, heb, hdb, outf, bar);

  k_persist<<<256, 256, 0, stream>>>(
      emb, aw, lens,
      Wih_e, Whh_e, bih_e, bhh_e,
      Wih_d, Whh_d, bih_d, bhh_d,
      ec0, dc0, Wo1, bo1, Wo2, maskp,
      heb, hdb, ctxb, outf, bar);
}

// Round 6
// 33907.172 us; speedup vs baseline: 9.7729x; 7.8430x over previous
//
#include <hip/hip_runtime.h>
#include <cstddef>

__device__ __forceinline__ float sigm(float x) { return 1.f / (1.f + __expf(-x)); }
__device__ __forceinline__ float tanh_(float x) { return 1.f - 2.f / (__expf(2.f * x) + 1.f); }

#define AGLD(p)    __hip_atomic_load((p),  __ATOMIC_RELAXED, __HIP_MEMORY_SCOPE_AGENT)
#define AGST(p, v) __hip_atomic_store((p), (v), __ATOMIC_RELAXED, __HIP_MEMORY_SCOPE_AGENT)

// 16-wide fp32 dot block: accumulates into a0..a3 (declared by caller)
#define DOT16(wp, hp, kk) do { \
    float4 w0_ = *(const float4*)((wp) + (kk));      float4 x0_ = *(const float4*)((hp) + (kk)); \
    float4 w1_ = *(const float4*)((wp) + (kk) + 4);  float4 x1_ = *(const float4*)((hp) + (kk) + 4); \
    float4 w2_ = *(const float4*)((wp) + (kk) + 8);  float4 x2_ = *(const float4*)((hp) + (kk) + 8); \
    float4 w3_ = *(const float4*)((wp) + (kk) + 12); float4 x3_ = *(const float4*)((hp) + (kk) + 12); \
    a0 = fmaf(w0_.x, x0_.x, a0); a0 = fmaf(w0_.y, x0_.y, a0); a0 = fmaf(w0_.z, x0_.z, a0); a0 = fmaf(w0_.w, x0_.w, a0); \
    a1 = fmaf(w1_.x, x1_.x, a1); a1 = fmaf(w1_.y, x1_.y, a1); a1 = fmaf(w1_.z, x1_.z, a1); a1 = fmaf(w1_.w, x1_.w, a1); \
    a2 = fmaf(w2_.x, x2_.x, a2); a2 = fmaf(w2_.y, x2_.y, a2); a2 = fmaf(w2_.z, x2_.z, a2); a2 = fmaf(w2_.w, x2_.w, a2); \
    a3 = fmaf(w3_.x, x3_.x, a3); a3 = fmaf(w3_.y, x3_.y, a3); a3 = fmaf(w3_.z, x3_.z, a3); a3 = fmaf(w3_.w, x3_.w, a3); \
  } while (0)

// ---------------- K1: embed = relu(inputs @ W_e^T + b_e), layout [s][b][e] ----------------
__global__ __launch_bounds__(256) void k_embed(
    const float* __restrict__ inp, const float* __restrict__ We,
    const float* __restrict__ be, float* __restrict__ emb)
{
  __shared__ float sA[32 * 68];
  __shared__ float sW[32 * 132];
  const int tid = threadIdx.x;
  const int b  = blockIdx.x >> 4;
  const int s0 = (blockIdx.x & 15) << 6;
  float acc[4][8];
#pragma unroll
  for (int i = 0; i < 4; ++i)
#pragma unroll
    for (int j = 0; j < 8; ++j) acc[i][j] = 0.f;
  const int m4 = (tid & 15) << 2;
  const int e8 = (tid >> 4) << 3;
  const float* Ab = inp + ((size_t)(b << 10) + s0) * 1024;
  const int ms = tid >> 2, kq = tid & 3;
  const int es = tid >> 1, kq2 = tid & 1;
  for (int k0 = 0; k0 < 1024; k0 += 32) {
    __syncthreads();
    {
      const float* src = Ab + (size_t)ms * 1024 + k0 + (kq << 3);
      float4 v0 = *(const float4*)(src);
      float4 v1 = *(const float4*)(src + 4);
      int kb = kq << 3;
      sA[(kb+0)*68+ms] = v0.x; sA[(kb+1)*68+ms] = v0.y;
      sA[(kb+2)*68+ms] = v0.z; sA[(kb+3)*68+ms] = v0.w;
      sA[(kb+4)*68+ms] = v1.x; sA[(kb+5)*68+ms] = v1.y;
      sA[(kb+6)*68+ms] = v1.z; sA[(kb+7)*68+ms] = v1.w;
    }
    {
      const float* src = We + (size_t)es * 1024 + k0 + (kq2 << 4);
#pragma unroll
      for (int q = 0; q < 4; ++q) {
        float4 v = *(const float4*)(src + (q << 2));
        int kb = (kq2 << 4) + (q << 2);
        sW[(kb+0)*132+es] = v.x; sW[(kb+1)*132+es] = v.y;
        sW[(kb+2)*132+es] = v.z; sW[(kb+3)*132+es] = v.w;
      }
    }
    __syncthreads();
#pragma unroll 4
    for (int kk = 0; kk < 32; ++kk) {
      float4 a4 = *(const float4*)&sA[kk*68 + m4];
      float4 b0 = *(const float4*)&sW[kk*132 + e8];
      float4 b1 = *(const float4*)&sW[kk*132 + e8 + 4];
      float av[4] = {a4.x, a4.y, a4.z, a4.w};
      float bv[8] = {b0.x, b0.y, b0.z, b0.w, b1.x, b1.y, b1.z, b1.w};
#pragma unroll
      for (int i = 0; i < 4; ++i)
#pragma unroll
        for (int j = 0; j < 8; ++j) acc[i][j] = fmaf(av[i], bv[j], acc[i][j]);
    }
  }
#pragma unroll
  for (int i = 0; i < 4; ++i) {
    int s = s0 + m4 + i;
#pragma unroll
    for (int j = 0; j < 8; ++j) {
      float v = acc[i][j] + be[e8 + j];
      emb[((size_t)(s << 5) + b) * 128 + e8 + j] = v > 0.f ? v : 0.f;
    }
  }
}

// ---------------- K2: a = relu(embed @ Wa1^T + ba1) @ Wa2^T + ba2, layout [s*32+b][3] ----------------
__global__ __launch_bounds__(256) void k_attn(
    const float* __restrict__ emb, const float* __restrict__ Wa1,
    const float* __restrict__ ba1, const float* __restrict__ Wa2,
    const float* __restrict__ ba2, float* __restrict__ aw)
{
  __shared__ float sE[2 * 128];
  __shared__ float sH[2 * 128];
  const int tid = threadIdx.x;
  const int rs0 = blockIdx.x * 2;
  sE[tid] = emb[(size_t)rs0 * 128 + tid];
  __syncthreads();
  const int half = tid >> 7, j = tid & 127;
  const float* w = Wa1 + j * 128;
  const float* e = sE + half * 128;
  float a0 = 0.f, a1 = 0.f, a2 = 0.f, a3 = 0.f;
  for (int k = 0; k < 128; k += 16) DOT16(w, e, k);
  float h = (a0 + a1) + (a2 + a3) + ba1[j];
  sH[half * 128 + j] = h > 0.f ? h : 0.f;
  __syncthreads();
  if (tid < 6) {
    int hh = tid / 3, l = tid % 3;
    const float* w2 = Wa2 + l * 128;
    const float* hv = sH + hh * 128;
    float s = 0.f;
    for (int k = 0; k < 128; ++k) s = fmaf(w2[k], hv[k], s);
    aw[(size_t)(rs0 + hh) * 3 + l] = s + ba2[l];
  }
}

// ---------------- K2b: softmax over time (axis s) per (b, l), in-place ----------------
__global__ __launch_bounds__(256) void k_softmax(float* __restrict__ aw)
{
  __shared__ float red[256];
  const int b = blockIdx.x / 3, l = blockIdx.x % 3;
  const int tid = threadIdx.x;
  float v[4];
#pragma unroll
  for (int i = 0; i < 4; ++i) {
    int s = tid + i * 256;
    v[i] = aw[(size_t)(s * 32 + b) * 3 + l];
  }
  float mx = fmaxf(fmaxf(v[0], v[1]), fmaxf(v[2], v[3]));
  red[tid] = mx;
  __syncthreads();
  for (int off = 128; off > 0; off >>= 1) {
    if (tid < off) red[tid] = fmaxf(red[tid], red[tid + off]);
    __syncthreads();
  }
  mx = red[0];
  __syncthreads();
  float sm = 0.f;
#pragma unroll
  for (int i = 0; i < 4; ++i) sm += __expf(v[i] - mx);
  red[tid] = sm;
  __syncthreads();
  for (int off = 128; off > 0; off >>= 1) {
    if (tid < off) red[tid] += red[tid + off];
    __syncthreads();
  }
  float inv = 1.f / red[0];
#pragma unroll
  for (int i = 0; i < 4; ++i) {
    int s = tid + i * 256;
    aw[(size_t)(s * 32 + b) * 3 + l] = __expf(v[i] - mx) * inv;
  }
}

// ---------------- K_prep: repack Wih_d (516-stride, aligned) + pre-summed biases ----------------
__global__ __launch_bounds__(256) void k_prep(
    const float* __restrict__ Wih_d,
    const float* __restrict__ bih_e, const float* __restrict__ bhh_e,
    const float* __restrict__ bih_d, const float* __restrict__ bhh_d,
    float* __restrict__ wdpack, float* __restrict__ bsum_e, float* __restrict__ bsum_d)
{
  const int row = blockIdx.x;           // 2048 rows
  const int tid = threadIdx.x;
  for (int q = tid; q < 516; q += 256) {
    float v = 0.f;
    if (q < 512)      v = Wih_d[(size_t)row * 513 + 1 + q];   // ctx part
    else if (q == 512) v = Wih_d[(size_t)row * 513];          // p coefficient
    wdpack[(size_t)row * 516 + q] = v;
  }
  if (tid == 0) {
    bsum_e[row] = bih_e[row] + bhh_e[row];
    bsum_d[row] = bih_d[row] + bhh_d[row];
  }
}

// ---------------- K_init: initial states + d_out = b_o2 + barrier zero ----------------
__global__ __launch_bounds__(256) void k_init(
    const float* __restrict__ eh0, const float* __restrict__ dh0,
    const float* __restrict__ bo2,
    float* __restrict__ heb, float* __restrict__ hdb,
    float* __restrict__ out, unsigned* __restrict__ bar)
{
  const int i = blockIdx.x * 256 + threadIdx.x;   // 32768 threads
  if (i < 16384) {
    int k = i & 511;
    heb[16384 + i] = eh0[k];   // slot 1 == slot for t=-1
    hdb[i] = dh0[k];           // single buffer, holds h_d(t-1)
  }
  out[i] = bo2[0];
  if (i < 1024) bar[i] = 0u;
}

// ---------------- per-batch barrier: 8 wgs, UC atomics only, NO cache fences ----------------
// All cross-wg data moves via relaxed agent-scope atomics (bypass L1/L2, live at the
// coherence point), so no wbl2/inv is ever needed -> weights stay hot in L2.
// __syncthreads() drains each wave's outstanding stores (compiler emits full s_waitcnt
// before s_barrier), so arrivals strictly follow the data publishes.
__device__ __forceinline__ void batchbar(unsigned* cnt, unsigned* flag, unsigned gen)
{
  __builtin_amdgcn_s_waitcnt(0);     // belt & braces: drain this wave's stores/atomics
  __syncthreads();
  if (threadIdx.x == 0) {
    asm volatile("" ::: "memory");
    unsigned old = __hip_atomic_fetch_add(cnt, 1u, __ATOMIC_RELAXED, __HIP_MEMORY_SCOPE_AGENT);
    if (old == (gen << 3) - 1u)      // last of this batch's 8 wgs
      AGST(flag, gen);
    while (AGLD(flag) < gen)
      __builtin_amdgcn_s_sleep(1);
    asm volatile("" ::: "memory");
  }
  __syncthreads();
}

// ---------------- K_persist: 32 independent per-batch pipelines ----------------
// wg = (b = blockIdx>>3, s = blockIdx&7). Slice s owns h-dims [s*64, s*64+64) of BOTH
// LSTMs (gate rows gamma*512 + s*64 + jl) and e-dims [s*16, s*16+16) of the out-MLP.
// s == blockIdx%8 pins each slice to one XCD (if round-robin holds) -> its ~1.2 MB of
// weight rows stay L2-resident. Weights are read-only -> plain cached loads, never stale.
__global__ __launch_bounds__(256) void k_persist(
    const float* __restrict__ emb, const float* __restrict__ aw,
    const int* __restrict__ lens,
    const float* __restrict__ Wih_e, const float* __restrict__ Whh_e,
    const float* __restrict__ Whh_d, const float* __restrict__ wdpack,
    const float* __restrict__ bsum_e, const float* __restrict__ bsum_d,
    const float* __restrict__ ec0, const float* __restrict__ dc0,
    const float* __restrict__ Wo1, const float* __restrict__ bo1,
    const float* __restrict__ Wo2, const float* __restrict__ maskp,
    float* __restrict__ heb, float* __restrict__ hdb,
    float* __restrict__ ctxb, float* __restrict__ out,
    unsigned* __restrict__ bar)
{
  __shared__ float sHe[512], sHd[512], sCtx[512], sEmb[128];
  __shared__ float sG[256];
  __shared__ float sPv;
  const int tid = threadIdx.x;
  const int b = blockIdx.x >> 3, s = blockIdx.x & 7;
  const int lane = tid & 63, w = tid >> 6;
  const int r8 = lane >> 3, kg = lane & 7;
  unsigned* cnt  = bar + b * 32;
  unsigned* flag = bar + b * 32 + 16;

  // cell-state registers (tid < 64 owns h-dim s*64+tid)
  float c_e = 0.f, c_d = 0.f, hm1 = 0.f, hm2 = 0.f;
  int len_b = lens[b];
  if (tid < 64) {
    c_e = ec0[(s << 6) + tid];
    c_d = dc0[(s << 6) + tid];
  }

  unsigned gen = 0;

  for (int t = 0; t < 1024; ++t) {
    // ================= phase A =================
    {  // stage h_e(t-1), h_d(t-1) (UC), emb[t] (cached)
      const float* hep = heb + (size_t)((t + 1) & 1) * 16384 + b * 512;
      const float* hdp = hdb + b * 512;
      sHe[tid]       = AGLD(hep + tid);
      sHe[tid + 256] = AGLD(hep + tid + 256);
      sHd[tid]       = AGLD(hdp + tid);
      sHd[tid + 256] = AGLD(hdp + tid + 256);
      if (tid < 128) sEmb[tid] = emb[(size_t)(t * 32 + b) * 128 + tid];
    }
    __syncthreads();

    // out-MLP duty for step t-1 (e-slice s*16..s*16+16), from staged sHd = h_d(t-1)
    if (t > 0) {
      const int e = (s << 4) + (tid >> 4), ks = tid & 15;
      const float4* wo = (const float4*)(Wo1 + (size_t)e * 512);
      const float4* hd4 = (const float4*)sHd;
      float a0 = 0.f, a1 = 0.f, a2 = 0.f, a3 = 0.f;
#pragma unroll
      for (int j4 = 0; j4 < 8; j4 += 4) {
        float4 wv0 = wo[(j4+0) * 16 + ks], hv0 = hd4[(j4+0) * 16 + ks];
        float4 wv1 = wo[(j4+1) * 16 + ks], hv1 = hd4[(j4+1) * 16 + ks];
        float4 wv2 = wo[(j4+2) * 16 + ks], hv2 = hd4[(j4+2) * 16 + ks];
        float4 wv3 = wo[(j4+3) * 16 + ks], hv3 = hd4[(j4+3) * 16 + ks];
        a0 = fmaf(wv0.x,hv0.x,a0); a0 = fmaf(wv0.y,hv0.y,a0); a0 = fmaf(wv0.z,hv0.z,a0); a0 = fmaf(wv0.w,hv0.w,a0);
        a1 = fmaf(wv1.x,hv1.x,a1); a1 = fmaf(wv1.y,hv1.y,a1); a1 = fmaf(wv1.z,hv1.z,a1); a1 = fmaf(wv1.w,hv1.w,a1);
        a2 = fmaf(wv2.x,hv2.x,a2); a2 = fmaf(wv2.y,hv2.y,a2); a2 = fmaf(wv2.z,hv2.z,a2); a2 = fmaf(wv2.w,hv2.w,a2);
        a3 = fmaf(wv3.x,hv3.x,a3); a3 = fmaf(wv3.y,hv3.y,a3); a3 = fmaf(wv3.z,hv3.z,a3); a3 = fmaf(wv3.w,hv3.w,a3);
      }
      float p_ = (a0 + a1) + (a2 + a3);
      p_ += __shfl_down(p_, 8);
      p_ += __shfl_down(p_, 4);
      p_ += __shfl_down(p_, 2);
      p_ += __shfl_down(p_, 1);
      float contrib = 0.f;
      if (ks == 0) {
        float q = p_ + bo1[e];
        contrib = (q > 0.f ? q : 0.f) * Wo2[e];
      }
      contrib += __shfl(contrib, 16) + __shfl(contrib, 32) + __shfl(contrib, 48);
      if (lane == 0) atomicAdd(&out[b * 1024 + (t - 1)], contrib);
    }

    // encoder gates: 256 rows, 8 passes of (4 waves x 8 rows x 8 k-groups)
#pragma unroll 2
    for (int pass = 0; pass < 8; ++pass) {
      const int rho = pass * 32 + w * 8 + r8;
      const int grow = ((rho >> 6) << 9) + (s << 6) + (rho & 63);
      const float4* wr = (const float4*)(Whh_e + (size_t)grow * 512);
      const float4* hr = (const float4*)sHe;
      float a0 = 0.f, a1 = 0.f, a2 = 0.f, a3 = 0.f;
#pragma unroll
      for (int kc = 0; kc < 16; kc += 4) {
        float4 w0 = wr[(kc+0)*8+kg], h0 = hr[(kc+0)*8+kg];
        float4 w1 = wr[(kc+1)*8+kg], h1 = hr[(kc+1)*8+kg];
        float4 w2 = wr[(kc+2)*8+kg], h2 = hr[(kc+2)*8+kg];
        float4 w3 = wr[(kc+3)*8+kg], h3 = hr[(kc+3)*8+kg];
        a0 = fmaf(w0.x,h0.x,a0); a0 = fmaf(w0.y,h0.y,a0); a0 = fmaf(w0.z,h0.z,a0); a0 = fmaf(w0.w,h0.w,a0);
        a1 = fmaf(w1.x,h1.x,a1); a1 = fmaf(w1.y,h1.y,a1); a1 = fmaf(w1.z,h1.z,a1); a1 = fmaf(w1.w,h1.w,a1);
        a2 = fmaf(w2.x,h2.x,a2); a2 = fmaf(w2.y,h2.y,a2); a2 = fmaf(w2.z,h2.z,a2); a2 = fmaf(w2.w,h2.w,a2);
        a3 = fmaf(w3.x,h3.x,a3); a3 = fmaf(w3.y,h3.y,a3); a3 = fmaf(w3.z,h3.z,a3); a3 = fmaf(w3.w,h3.w,a3);
      }
      const float4* wx = (const float4*)(Wih_e + (size_t)grow * 128);
      const float4* xr = (const float4*)sEmb;
#pragma unroll
      for (int kc = 0; kc < 4; ++kc) {
        float4 wv = wx[kc*8+kg], xv = xr[kc*8+kg];
        a0 = fmaf(wv.x,xv.x,a0); a1 = fmaf(wv.y,xv.y,a1);
        a2 = fmaf(wv.z,xv.z,a2); a3 = fmaf(wv.w,xv.w,a3);
      }
      float p = (a0 + a1) + (a2 + a3);
      p += __shfl_down(p, 4);
      p += __shfl_down(p, 2);
      p += __shfl_down(p, 1);
      if (kg == 0) sG[rho] = p + bsum_e[grow];
    }
    __syncthreads();

    // enc cell + publish h_e slice and ctx slice (UC)
    if (tid < 64) {
      float gi = sG[tid], gf = sG[64 + tid], gg = sG[128 + tid], go = sG[192 + tid];
      c_e = sigm(gf) * c_e + sigm(gi) * tanh_(gg);
      float h = sigm(go) * tanh_(c_e);
      int ci = b * 512 + (s << 6) + tid;
      AGST(&heb[(size_t)(t & 1) * 16384 + ci], h);
      float hmv = (t < len_b) ? h : 0.f;
      const float* at = aw + (size_t)(t * 32 + b) * 3;
      float ctx = at[0] * hmv + at[1] * hm1 + at[2] * hm2;
      hm2 = hm1; hm1 = hmv;
      AGST(&ctxb[ci], ctx);
    }
    batchbar(cnt, flag, ++gen);

    // ================= phase B =================
    {  // stage ctx(t) (UC) + p(t-1)
      const float* cp = ctxb + b * 512;
      sCtx[tid]       = AGLD(cp + tid);
      sCtx[tid + 256] = AGLD(cp + tid + 256);
      if (tid == 0) sPv = (t == 0) ? 0.f : AGLD(&out[b * 1024 + (t - 1)]);
    }
    __syncthreads();

    // decoder gates: 256 rows (sHd still holds h_d(t-1))
#pragma unroll 2
    for (int pass = 0; pass < 8; ++pass) {
      const int rho = pass * 32 + w * 8 + r8;
      const int grow = ((rho >> 6) << 9) + (s << 6) + (rho & 63);
      const float4* wh = (const float4*)(Whh_d + (size_t)grow * 512);
      const float4* wc = (const float4*)(wdpack + (size_t)grow * 516);
      const float4* hr = (const float4*)sHd;
      const float4* cr = (const float4*)sCtx;
      float a0 = 0.f, a1 = 0.f, a2 = 0.f, a3 = 0.f;
#pragma unroll
      for (int kc = 0; kc < 16; kc += 2) {
        float4 w0 = wh[(kc+0)*8+kg], h0 = hr[(kc+0)*8+kg];
        float4 w1 = wh[(kc+1)*8+kg], h1 = hr[(kc+1)*8+kg];
        float4 v0 = wc[(kc+0)*8+kg], c0 = cr[(kc+0)*8+kg];
        float4 v1 = wc[(kc+1)*8+kg], c1 = cr[(kc+1)*8+kg];
        a0 = fmaf(w0.x,h0.x,a0); a0 = fmaf(w0.y,h0.y,a0); a0 = fmaf(w0.z,h0.z,a0); a0 = fmaf(w0.w,h0.w,a0);
        a1 = fmaf(w1.x,h1.x,a1); a1 = fmaf(w1.y,h1.y,a1); a1 = fmaf(w1.z,h1.z,a1); a1 = fmaf(w1.w,h1.w,a1);
        a2 = fmaf(v0.x,c0.x,a2); a2 = fmaf(v0.y,c0.y,a2); a2 = fmaf(v0.z,c0.z,a2); a2 = fmaf(v0.w,c0.w,a2);
        a3 = fmaf(v1.x,c1.x,a3); a3 = fmaf(v1.y,c1.y,a3); a3 = fmaf(v1.z,c1.z,a3); a3 = fmaf(v1.w,c1.w,a3);
      }
      float p = (a0 + a1) + (a2 + a3);
      p += __shfl_down(p, 4);
      p += __shfl_down(p, 2);
      p += __shfl_down(p, 1);
      if (kg == 0)
        sG[rho] = p + sPv * wdpack[(size_t)grow * 516 + 512] + bsum_d[grow];
    }
    __syncthreads();

    // dec cell + publish h_d slice (UC)
    if (tid < 64) {
      float gi = sG[tid], gf = sG[64 + tid], gg = sG[128 + tid], go = sG[192 + tid];
      c_d = sigm(gf) * c_d + sigm(gi) * tanh_(gg);
      float h = sigm(go) * tanh_(c_d);
      AGST(&hdb[b * 512 + (s << 6) + tid], h);
    }
    batchbar(cnt, flag, ++gen);
  }

  // ---- final out-MLP duty for t = 1023 ----
  {
    const float* hdp = hdb + b * 512;
    sHd[tid]       = AGLD(hdp + tid);
    sHd[tid + 256] = AGLD(hdp + tid + 256);
  }
  __syncthreads();
  {
    const int e = (s << 4) + (tid >> 4), ks = tid & 15;
    const float4* wo = (const float4*)(Wo1 + (size_t)e * 512);
    const float4* hd4 = (const float4*)sHd;
    float a0 = 0.f, a1 = 0.f, a2 = 0.f, a3 = 0.f;
#pragma unroll
    for (int j4 = 0; j4 < 8; ++j4) {
      float4 wv = wo[j4 * 16 + ks], hv = hd4[j4 * 16 + ks];
      a0 = fmaf(wv.x,hv.x,a0); a1 = fmaf(wv.y,hv.y,a1);
      a2 = fmaf(wv.z,hv.z,a2); a3 = fmaf(wv.w,hv.w,a3);
    }
    float p_ = (a0 + a1) + (a2 + a3);
    p_ += __shfl_down(p_, 8);
    p_ += __shfl_down(p_, 4);
    p_ += __shfl_down(p_, 2);
    p_ += __shfl_down(p_, 1);
    float contrib = 0.f;
    if (ks == 0) {
      float q = p_ + bo1[e];
      contrib = (q > 0.f ? q : 0.f) * Wo2[e];
    }
    contrib += __shfl(contrib, 16) + __shfl(contrib, 32) + __shfl(contrib, 48);
    if (lane == 0) atomicAdd(&out[b * 1024 + 1023], contrib);
  }
  batchbar(cnt, flag, ++gen);

  // ---- mask own slice: out[b][s*128 .. s*128+128) ----
  if (tid < 128) {
    int idx = b * 1024 + (s << 7) + tid;
    float v = AGLD(&out[idx]);
    out[idx] = v * maskp[idx];
  }
}

extern "C" void kernel_launch(void* const* d_in, const int* in_sizes, int n_in,
                              void* d_out, int out_size, void* d_ws, size_t ws_size,
                              hipStream_t stream)
{
  const float* inp   = (const float*)d_in[0];
  const float* maskp = (const float*)d_in[1];
  const int*   lens  = (const int*)d_in[2];
  const float* We    = (const float*)d_in[3];
  const float* be    = (const float*)d_in[4];
  const float* Wa1   = (const float*)d_in[5];
  const float* ba1   = (const float*)d_in[6];
  const float* Wa2   = (const float*)d_in[7];
  const float* ba2   = (const float*)d_in[8];
  const float* Wih_e = (const float*)d_in[9];
  const float* Whh_e = (const float*)d_in[10];
  const float* bih_e = (const float*)d_in[11];
  const float* bhh_e = (const float*)d_in[12];
  const float* eh0   = (const float*)d_in[13];
  const float* ec0   = (const float*)d_in[14];
  const float* Wih_d = (const float*)d_in[15];
  const float* Whh_d = (const float*)d_in[16];
  const float* bih_d = (const float*)d_in[17];
  const float* bhh_d = (const float*)d_in[18];
  const float* dh0   = (const float*)d_in[19];
  const float* dc0   = (const float*)d_in[20];
  const float* Wo1   = (const float*)d_in[21];
  const float* bo1   = (const float*)d_in[22];
  const float* Wo2   = (const float*)d_in[23];
  const float* bo2   = (const float*)d_in[24];

  float* ws     = (float*)d_ws;
  float* emb    = ws;                     // 4,194,304
  float* aw     = emb + 4194304;          //    98,304
  float* heb    = aw + 98304;             //    32,768 (2 slots)
  float* hdb    = heb + 32768;            //    16,384
  float* ctxb   = hdb + 16384;            //    16,384
  float* wdpack = ctxb + 16384;           // 1,056,768 (2048 x 516)
  float* bsum_e = wdpack + 1056768;       //     2,048
  float* bsum_d = bsum_e + 2048;          //     2,048
  unsigned* bar = (unsigned*)(bsum_d + 2048);  // 1,024
  float* outf = (float*)d_out;

  k_embed<<<512, 256, 0, stream>>>(inp, We, be, emb);
  k_attn<<<16384, 256, 0, stream>>>(emb, Wa1, ba1, Wa2, ba2, aw);
  k_softmax<<<96, 256, 0, stream>>>(aw);
  k_prep<<<2048, 256, 0, stream>>>(Wih_d, bih_e, bhh_e, bih_d, bhh_d,
                                   wdpack, bsum_e, bsum_d);
  k_init<<<128, 256, 0, stream>>>(eh0, dh0, bo2, heb, hdb, outf, bar);

  k_persist<<<256, 256, 0, stream>>>(
      emb, aw, lens,
      Wih_e, Whh_e, Whh_d, wdpack, bsum_e, bsum_d,
      ec0, dc0, Wo1, bo1, Wo2, maskp,
      heb, hdb, ctxb, outf, bar);
}